// Round 1
// baseline (258.922 us; speedup 1.0000x reference)
//
#include <hip/hip_runtime.h>

typedef unsigned short ushort_t;
typedef __attribute__((ext_vector_type(8))) short bf16x8;
typedef __attribute__((ext_vector_type(4))) float f32x4;

#define C_DIM 64
#define P_DIM 1296
#define N_DIM 2000
#define B_DIM 256
#define K_DIM (C_DIM * P_DIM)              // 82944
#define XB_ELEMS (B_DIM * K_DIM)           // 21233664
#define XB_ELEMS_PAD (XB_ELEMS + 256)      // 21233920
#define XB_BYTES ((size_t)XB_ELEMS_PAD * 2) // 42467840
#define SLICES 32
#define OUT_ELEMS (B_DIM * N_DIM)          // 512000

static __device__ __forceinline__ ushort_t f2bf(float f) {
  unsigned u = __builtin_bit_cast(unsigned, f);
  u += 0x7fffu + ((u >> 16) & 1u);
  return (ushort_t)(u >> 16);
}

// ---------------- x (fp32) -> Xb (bf16) with zeroed pad tail ----------------
__global__ void klindt_cvt_kernel(const float4* __restrict__ x,
                                  unsigned long long* __restrict__ xb) {
  int idx = blockIdx.x * 256 + threadIdx.x;
  if (idx >= XB_ELEMS_PAD / 4) return;
  unsigned long long r = 0ull;
  if (idx < XB_ELEMS / 4) {
    float4 v = x[idx];
    r = (unsigned long long)f2bf(v.x) | ((unsigned long long)f2bf(v.y) << 16) |
        ((unsigned long long)f2bf(v.z) << 32) |
        ((unsigned long long)f2bf(v.w) << 48);
  }
  xb[idx] = r;
}

// ---------------- main GEMM: partials[slice][b][n] ----------------
// Tile: BM=256 (full M), BN=128, BK=32. 512 threads = 8 waves (4 M x 2 N),
// each wave owns a 64x64 output sub-tile = acc[4][4] of 16x16 frags.
// Grid: (16 n-tiles, 32 K-slices of 2 channels each).
__global__ void __launch_bounds__(512, 4) klindt_gemm_kernel(
    const ushort_t* __restrict__ xb, const float* __restrict__ mw,
    const float* __restrict__ rw, float* __restrict__ partials) {
  __shared__ ushort_t sA[2][8192];  // [256 rows][32 k] bf16, 64B rows
  __shared__ ushort_t sB[2][4096];  // [128 n][32 k]  bf16, 64B rows

  const int tid = threadIdx.x;
  const int lane = tid & 63;
  const int wid = tid >> 6;
  const int wm = wid >> 1;  // 0..3
  const int wn = wid & 1;   // 0..1
  const int n0 = blockIdx.x * 128;
  const int slice = blockIdx.y;  // 0..31
  const int c0 = slice * 2;

  f32x4 acc[4][4];
#pragma unroll
  for (int i = 0; i < 4; ++i)
#pragma unroll
    for (int j = 0; j < 4; ++j) {
      acc[i][j][0] = 0.f; acc[i][j][1] = 0.f;
      acc[i][j][2] = 0.f; acc[i][j][3] = 0.f;
    }

  // ---- per-thread staging constants ----
  // A: chunk = it*512+tid -> dest row=chunk>>2, slot=chunk&3 (linear LDS dest),
  //    source slot XOR-swizzled so LDS holds swizzled layout (rule #21).
  int a_row[2], a_soff[2], a_doff[2];
#pragma unroll
  for (int it = 0; it < 2; ++it) {
    int chunk = it * 512 + tid;
    int row = chunk >> 2, t4 = chunk & 3;
    int ss = t4 ^ ((row >> 1) & 3);
    a_row[it] = row;
    a_soff[it] = ss * 8;     // elements
    a_doff[it] = chunk * 8;  // elements (byte = chunk*16, linear)
  }
  // B: idx = it*512+tid: n_low=idx&15, kq=(idx>>4)&7, n_hi=idx>>7.
  //    Thread loads 4 consecutive k (=p) for one n, packs b64, swizzled write.
  int b_kq[2], b_ng[2], b_eoff[2];
#pragma unroll
  for (int it = 0; it < 2; ++it) {
    int idx = it * 512 + tid;
    int nl = idx & 15, kq = (idx >> 4) & 7, nh = idx >> 7;
    int n = nh * 16 + nl;
    b_kq[it] = kq;
    b_ng[it] = n0 + n;
    int slotp = (kq >> 1) ^ ((nl >> 1) & 3);
    b_eoff[it] = n * 32 + slotp * 8 + (kq & 1) * 4;  // elements, 8B aligned
  }

  // ---- fragment read offsets (swizzle-consistent) ----
  const int r15 = lane & 15, g4 = lane >> 4;
  const int swz = g4 ^ ((r15 >> 1) & 3);
  const int aoffbase = (wm * 64 + r15) * 32 + swz * 8;
  const int boffbase = (wn * 64 + r15) * 32 + swz * 8;

  float mv[2][4];
  float rv[2];

  auto issueA = [&](int buf, int k0) {
#pragma unroll
    for (int it = 0; it < 2; ++it) {
      const ushort_t* g = xb + (size_t)a_row[it] * K_DIM + k0 + a_soff[it];
      __builtin_amdgcn_global_load_lds(
          (const __attribute__((address_space(1))) unsigned int*)g,
          (__attribute__((address_space(3))) unsigned int*)(&sA[buf][a_doff[it]]),
          16, 0, 0);
    }
  };
  auto issueB = [&](int c, int p0) {
#pragma unroll
    for (int it = 0; it < 2; ++it) {
      const int ng = b_ng[it];
      const bool okn = ng < N_DIM;
      rv[it] = okn ? rw[c * N_DIM + ng] : 0.f;
#pragma unroll
      for (int j = 0; j < 4; ++j) {
        int p = p0 + b_kq[it] * 4 + j;
        mv[it][j] = (okn && p < P_DIM)
                        ? mw[(size_t)p * (C_DIM * N_DIM) + c * N_DIM + ng]
                        : 0.f;
      }
    }
  };
  auto writeB = [&](int buf) {
#pragma unroll
    for (int it = 0; it < 2; ++it) {
      unsigned long long pk = 0ull;
#pragma unroll
      for (int j = 0; j < 4; ++j)
        pk |= (unsigned long long)f2bf(mv[it][j] * rv[it]) << (16 * j);
      *(unsigned long long*)(&sB[buf][b_eoff[it]]) = pk;
    }
  };
  auto computeStep = [&](int buf) {
    bf16x8 bfr[4];
#pragma unroll
    for (int fn = 0; fn < 4; ++fn)
      bfr[fn] = *(const bf16x8*)(&sB[buf][boffbase + fn * 512]);
#pragma unroll
    for (int fm = 0; fm < 4; ++fm) {
      bf16x8 afr = *(const bf16x8*)(&sA[buf][aoffbase + fm * 512]);
#pragma unroll
      for (int fn = 0; fn < 4; ++fn)
        acc[fm][fn] = __builtin_amdgcn_mfma_f32_16x16x32_bf16(
            afr, bfr[fn], acc[fm][fn], 0, 0, 0);
    }
  };

  // prologue: stage step 0 into buf 0
  issueA(0, c0 * P_DIM);
  issueB(c0, 0);
  writeB(0);
  __syncthreads();

  const int NSTEP = 82;  // 2 channels x 41 BK-steps (last step zero-padded in B)
  for (int s = 0; s < NSTEP; ++s) {
    int buf = s & 1;
    int s1 = s + 1;
    if (s1 < NSTEP) {
      int half = (s1 >= 41) ? 1 : 0;
      int sp = s1 - 41 * half;
      int c = c0 + half;
      issueA(buf ^ 1, c * P_DIM + sp * 32);  // async -> LDS
      issueB(c, sp * 32);                    // global -> regs (issue early)
    }
    computeStep(buf);                        // MFMA hides load latency
    if (s1 < NSTEP) writeB(buf ^ 1);         // cvt + ds_write (write late)
    __syncthreads();
  }

  // epilogue: write fp32 partials for this K-slice
  float* pb = partials + (size_t)slice * OUT_ELEMS;
#pragma unroll
  for (int fm = 0; fm < 4; ++fm) {
#pragma unroll
    for (int fn = 0; fn < 4; ++fn) {
      int nn = n0 + wn * 64 + fn * 16 + r15;
      if (nn < N_DIM) {
#pragma unroll
        for (int rr = 0; rr < 4; ++rr) {
          int m = wm * 64 + fm * 16 + g4 * 4 + rr;
          pb[m * N_DIM + nn] = acc[fm][fn][rr];
        }
      }
    }
  }
}

// ---------------- deterministic split-K reduction ----------------
__global__ void klindt_reduce_kernel(const float* __restrict__ part,
                                     float* __restrict__ out) {
  int i = blockIdx.x * 256 + threadIdx.x;
  if (i < OUT_ELEMS) {
    float s = 0.f;
#pragma unroll
    for (int k = 0; k < SLICES; ++k) s += part[(size_t)k * OUT_ELEMS + i];
    out[i] = s;
  }
}

extern "C" void kernel_launch(void* const* d_in, const int* in_sizes, int n_in,
                              void* d_out, int out_size, void* d_ws,
                              size_t ws_size, hipStream_t stream) {
  (void)in_sizes; (void)n_in; (void)out_size; (void)ws_size;
  const float* x = (const float*)d_in[0];
  const float* mw = (const float*)d_in[1];
  const float* rw = (const float*)d_in[2];
  float* out = (float*)d_out;

  ushort_t* xb = (ushort_t*)d_ws;
  float* partials = (float*)((char*)d_ws + XB_BYTES);

  // 1) x -> bf16 (with zeroed pad tail)
  {
    int nvec = XB_ELEMS_PAD / 4;
    int grid = (nvec + 255) / 256;
    klindt_cvt_kernel<<<grid, 256, 0, stream>>>((const float4*)x,
                                                (unsigned long long*)xb);
  }
  // 2) GEMM with on-the-fly W = mw*rw -> bf16
  {
    dim3 grid(16, SLICES);
    klindt_gemm_kernel<<<grid, 512, 0, stream>>>(xb, mw, rw, partials);
  }
  // 3) reduce split-K partials
  {
    int grid = (OUT_ELEMS + 255) / 256;
    klindt_reduce_kernel<<<grid, 256, 0, stream>>>(partials, out);
  }
}

// Round 2
// 252.993 us; speedup vs baseline: 1.0234x; 1.0234x over previous
//
#include <hip/hip_runtime.h>

typedef unsigned short ushort_t;
typedef unsigned int uint_t;
typedef __attribute__((ext_vector_type(8))) short bf16x8;
typedef __attribute__((ext_vector_type(4))) float f32x4;

#define C_DIM 64
#define P_DIM 1296
#define N_DIM 2000
#define B_DIM 256
#define K_DIM (C_DIM * P_DIM)               // 82944
#define XB_ELEMS (B_DIM * K_DIM)            // 21233664
#define XB_ELEMS_PAD (XB_ELEMS + 256)       // 21233920
#define XB_BYTES ((size_t)XB_ELEMS_PAD * 2) // 42467840
#define SLICES 32
#define OUT_ELEMS (B_DIM * N_DIM)           // 512000
#define NSTEP 82                            // 2 channels x 41 BK=32 steps

static __device__ __forceinline__ ushort_t f2bf(float f) {
  unsigned u = __builtin_bit_cast(unsigned, f);
  u += 0x7fffu + ((u >> 16) & 1u);
  return (ushort_t)(u >> 16);
}

// ---------------- x (fp32) -> Xb (bf16) with zeroed pad tail ----------------
__global__ void klindt_cvt_kernel(const float4* __restrict__ x,
                                  unsigned long long* __restrict__ xb) {
  int idx = blockIdx.x * 256 + threadIdx.x;
  if (idx >= XB_ELEMS_PAD / 4) return;
  unsigned long long r = 0ull;
  if (idx < XB_ELEMS / 4) {
    float4 v = x[idx];
    r = (unsigned long long)f2bf(v.x) | ((unsigned long long)f2bf(v.y) << 16) |
        ((unsigned long long)f2bf(v.z) << 32) |
        ((unsigned long long)f2bf(v.w) << 48);
  }
  xb[idx] = r;
}

// ---------------- main GEMM: partials[slice][b][n] ----------------
// BM=256 (full M, mw read exactly once), BN=128, BK=32. 512 threads = 8 waves
// (4Mx2N), wave tile 64x64 = acc[4][4] of 16x16x32 bf16 MFMAs.
// T4 schedule: raw s_barrier + counted vmcnt(8); B (mw stream) register-
// prefetched 2 steps ahead (static parity), A via global_load_lds 1 ahead.
__global__ void __launch_bounds__(512, 4) klindt_gemm_kernel(
    const char* __restrict__ xbb, const char* __restrict__ mwb,
    const float* __restrict__ rw, float* __restrict__ partials) {
  __shared__ ushort_t sA[2][8192];  // [256 m][32 k] bf16, 64B rows, XOR-swz
  __shared__ ushort_t sB[2][4096];  // [128 n][32 k] bf16, 64B rows, XOR-swz

  const int tid = threadIdx.x;
  const int lane = tid & 63;
  const int wid = tid >> 6;
  const int wm = wid >> 1;
  const int wn = wid & 1;
  const int n0 = blockIdx.x * 128;
  const int slice = blockIdx.y;
  const int c0 = slice * 2;

  f32x4 acc[4][4];
#pragma unroll
  for (int i = 0; i < 4; ++i)
#pragma unroll
    for (int j = 0; j < 4; ++j) {
      acc[i][j][0] = 0.f; acc[i][j][1] = 0.f;
      acc[i][j][2] = 0.f; acc[i][j][3] = 0.f;
    }

  // ---- A staging constants: linear LDS dest, inverse-swizzled global src ----
  uint_t a_gbase[2]; int a_doff[2];
#pragma unroll
  for (int it = 0; it < 2; ++it) {
    int chunk = it * 512 + tid;
    int row = chunk >> 2, t4 = chunk & 3;
    int ss = t4 ^ ((row >> 1) & 3);
    a_gbase[it] = (uint_t)(row * K_DIM + ss * 8) * 2u;  // byte off into xb
    a_doff[it] = chunk * 8;                             // elem off into sA
  }
  // ---- B staging constants ----
  uint_t b_goff[2]; int b_eoff[2], b_kj[2]; bool b_ok[2];
  float rvl[2], rvh[2];
#pragma unroll
  for (int it = 0; it < 2; ++it) {
    int idx = it * 512 + tid;
    int nl = idx & 15, kq = (idx >> 4) & 7, nh = idx >> 7;
    int n = nh * 16 + nl;
    int ng = n0 + n;
    bool okn = ng < N_DIM;
    b_ok[it] = okn;
    b_kj[it] = kq * 4;
    b_goff[it] = (uint_t)kq * 2048000u + (uint_t)ng * 4u;  // byte off into mw
    int slotp = (kq >> 1) ^ ((nl >> 1) & 3);
    b_eoff[it] = n * 32 + slotp * 8 + (kq & 1) * 4;        // elem off into sB
    rvl[it] = okn ? rw[c0 * N_DIM + ng] : 0.f;
    rvh[it] = okn ? rw[(c0 + 1) * N_DIM + ng] : 0.f;
  }

  // ---- fragment read offsets (swizzle-consistent) ----
  const int r15 = lane & 15, g4 = lane >> 4;
  const int swz = g4 ^ ((r15 >> 1) & 3);
  const int aoffbase = (wm * 64 + r15) * 32 + swz * 8;
  const int boffbase = (wn * 64 + r15) * 32 + swz * 8;

  float mvE[2][4], mvO[2][4];  // B register double-buffer (static parity)

  auto issueA = [&](int buf, int t) {
    int half = (t >= 41) ? 1 : 0;
    int sp = t - 41 * half;
    uint_t kb = ((uint_t)(c0 + half) * (uint_t)P_DIM + (uint_t)sp * 32u) * 2u;
#pragma unroll
    for (int it = 0; it < 2; ++it) {
      const char* g = xbb + (a_gbase[it] + kb);
      __builtin_amdgcn_global_load_lds(
          (const __attribute__((address_space(1))) unsigned int*)g,
          (__attribute__((address_space(3))) unsigned int*)(&sA[buf][a_doff[it]]),
          16, 0, 0);
    }
  };
  auto computeStep = [&](int buf) {
    bf16x8 bfr[4];
#pragma unroll
    for (int fn = 0; fn < 4; ++fn)
      bfr[fn] = *(const bf16x8*)(&sB[buf][boffbase + fn * 512]);
#pragma unroll
    for (int fm = 0; fm < 4; ++fm) {
      bf16x8 afr = *(const bf16x8*)(&sA[buf][aoffbase + fm * 512]);
#pragma unroll
      for (int fn = 0; fn < 4; ++fn)
        acc[fm][fn] = __builtin_amdgcn_mfma_f32_16x16x32_bf16(
            afr, bfr[fn], acc[fm][fn], 0, 0, 0);
    }
  };

#define ISSUE_B(MV, T)                                                        \
  do {                                                                        \
    int half_ = ((T) >= 41) ? 1 : 0;                                          \
    int sp_ = (T)-41 * half_;                                                 \
    uint_t ub_ = (uint_t)sp_ * 16384000u + (uint_t)(c0 + half_) * 8000u;      \
    bool full_ = (sp_ < 40);                                                  \
    _Pragma("unroll") for (int it_ = 0; it_ < 2; ++it_) {                     \
      const char* bp_ = mwb + (ub_ + b_goff[it_]);                            \
      _Pragma("unroll") for (int j_ = 0; j_ < 4; ++j_) {                      \
        bool ok_ = b_ok[it_] && (full_ || (b_kj[it_] + j_) < 16);             \
        MV[it_][j_] = ok_ ? *(const float*)(bp_ + (uint_t)j_ * 512000u) : 0.f;\
      }                                                                       \
    }                                                                         \
  } while (0)

#define WRITE_B(BUF, MV, T)                                                   \
  do {                                                                        \
    bool hi_ = ((T) >= 41);                                                   \
    _Pragma("unroll") for (int it_ = 0; it_ < 2; ++it_) {                     \
      float r_ = hi_ ? rvh[it_] : rvl[it_];                                   \
      unsigned long long pk_ = 0ull;                                          \
      _Pragma("unroll") for (int j_ = 0; j_ < 4; ++j_)                        \
        pk_ |= (unsigned long long)f2bf(MV[it_][j_] * r_) << (16 * j_);       \
      *(unsigned long long*)(&sB[BUF][b_eoff[it_]]) = pk_;                    \
    }                                                                         \
  } while (0)

  // ---- prologue ----
  ISSUE_B(mvE, 0);
  issueA(0, 0);
  WRITE_B(0, mvE, 0);     // compiler waits B(0) (counted), A(0) stays in flight
  ISSUE_B(mvO, 1);
  asm volatile("s_waitcnt vmcnt(8)\n\ts_waitcnt lgkmcnt(0)" ::: "memory");
  __builtin_amdgcn_sched_barrier(0);
  __builtin_amdgcn_s_barrier();
  __builtin_amdgcn_sched_barrier(0);

#define BODY(S, MV_ISSUE, MV_WRITE)                                           \
  {                                                                           \
    issueA(((S) + 1) & 1, (S) + 1);                                           \
    ISSUE_B(MV_ISSUE, (S) + 2);                                               \
    computeStep((S)&1);                                                       \
    WRITE_B(((S) + 1) & 1, MV_WRITE, (S) + 1);                                \
    asm volatile("s_waitcnt vmcnt(8)\n\ts_waitcnt lgkmcnt(0)" ::: "memory");  \
    __builtin_amdgcn_sched_barrier(0);                                        \
    __builtin_amdgcn_s_barrier();                                             \
    __builtin_amdgcn_sched_barrier(0);                                        \
  }

  // ---- main loop: steps 0..79 (all prefetches in range, no guards) ----
  for (int s = 0; s < 80; s += 2) {
    BODY(s, mvE, mvO);
    BODY(s + 1, mvO, mvE);
  }
  // ---- peel s=80 (no B prefetch; full drain so A(81) is guaranteed) ----
  issueA(1, 81);
  computeStep(0);
  WRITE_B(1, mvO, 81);
  asm volatile("s_waitcnt vmcnt(0)\n\ts_waitcnt lgkmcnt(0)" ::: "memory");
  __builtin_amdgcn_sched_barrier(0);
  __builtin_amdgcn_s_barrier();
  __builtin_amdgcn_sched_barrier(0);
  // ---- s=81 ----
  computeStep(1);

  // ---- epilogue: fp32 partials for this K-slice ----
  float* pb = partials + (size_t)slice * OUT_ELEMS;
#pragma unroll
  for (int fm = 0; fm < 4; ++fm) {
#pragma unroll
    for (int fn = 0; fn < 4; ++fn) {
      int nn = n0 + wn * 64 + fn * 16 + r15;
      if (nn < N_DIM) {
#pragma unroll
        for (int rr = 0; rr < 4; ++rr) {
          int m = wm * 64 + fm * 16 + g4 * 4 + rr;
          pb[m * N_DIM + nn] = acc[fm][fn][rr];
        }
      }
    }
  }
#undef BODY
#undef ISSUE_B
#undef WRITE_B
}

// ---------------- deterministic split-K reduction ----------------
__global__ void klindt_reduce_kernel(const float* __restrict__ part,
                                     float* __restrict__ out) {
  int i = blockIdx.x * 256 + threadIdx.x;
  if (i < OUT_ELEMS) {
    float s = 0.f;
#pragma unroll
    for (int k = 0; k < SLICES; ++k) s += part[(size_t)k * OUT_ELEMS + i];
    out[i] = s;
  }
}

extern "C" void kernel_launch(void* const* d_in, const int* in_sizes, int n_in,
                              void* d_out, int out_size, void* d_ws,
                              size_t ws_size, hipStream_t stream) {
  (void)in_sizes; (void)n_in; (void)out_size; (void)ws_size;
  const float* x = (const float*)d_in[0];
  const char* mwb = (const char*)d_in[1];
  const float* rw = (const float*)d_in[2];
  float* out = (float*)d_out;

  char* xbb = (char*)d_ws;
  float* partials = (float*)((char*)d_ws + XB_BYTES);

  {
    int nvec = XB_ELEMS_PAD / 4;
    int grid = (nvec + 255) / 256;
    klindt_cvt_kernel<<<grid, 256, 0, stream>>>((const float4*)x,
                                                (unsigned long long*)xbb);
  }
  {
    dim3 grid(16, SLICES);
    klindt_gemm_kernel<<<grid, 512, 0, stream>>>(xbb, mwb, rw, partials);
  }
  {
    int grid = (OUT_ELEMS + 255) / 256;
    klindt_reduce_kernel<<<grid, 256, 0, stream>>>(partials, out);
  }
}